// Round 2
// baseline (8933.725 us; speedup 1.0000x reference)
//
#include <hip/hip_runtime.h>
#include <hip/hip_cooperative_groups.h>
#include <math.h>

namespace cg = cooperative_groups;

// Problem constants (B=16, T=64, NN=4096, H=1024)
constexpr int kB = 16;
constexpr int kT = 64;
constexpr int kH = 1024;

// ---------------------------------------------------------------------------
// Tiled fp32 GEMM, "NT" form with bias:  C[M,N] = X[M,K] @ W[N,K]^T + bias[N]
// Block tile 64x64, K-tile 16, 256 threads, 4x4 micro-tile per thread.
// Pad = +4 floats: keeps tile rows 16B-aligned (ds_read_b128-able) and caps
// LDS write aliasing at 2-way (free). N%64==0, K%16==0 for all uses.
// ---------------------------------------------------------------------------
#define GBM 64
#define GBN 64
#define GBK 16
#define GPAD 4

__global__ __launch_bounds__(256)
void gemm_nt_bias(const float* __restrict__ X,   // [M,K]
                  const float* __restrict__ W,   // [N,K]
                  const float* __restrict__ bias,// [N]
                  float* __restrict__ C,         // [M,N]
                  int M, int N, int K)
{
    __shared__ float Xs[GBK][GBM + GPAD];
    __shared__ float Ws[GBK][GBN + GPAD];

    const int tid = threadIdx.x;          // 0..255
    const int bm = blockIdx.y * GBM;
    const int bn = blockIdx.x * GBN;
    const int tm = (tid >> 4) * 4;        // 0..60
    const int tn = (tid & 15) * 4;        // 0..60

    // loader mapping: each thread loads one float4 of each tile
    const int lr = tid >> 2;              // row within tile 0..63
    const int lc = (tid & 3) * 4;         // k within tile {0,4,8,12}

    float acc[4][4] = {};

    for (int k0 = 0; k0 < K; k0 += GBK) {
        // X tile (guarded rows)
        {
            const int gr = bm + lr;
            float4 v = make_float4(0.f, 0.f, 0.f, 0.f);
            if (gr < M) v = *(const float4*)(X + (long)gr * K + k0 + lc);
            Xs[lc + 0][lr] = v.x; Xs[lc + 1][lr] = v.y;
            Xs[lc + 2][lr] = v.z; Xs[lc + 3][lr] = v.w;
        }
        // W tile (always in bounds)
        {
            const int gr = bn + lr;
            const float4 v = *(const float4*)(W + (long)gr * K + k0 + lc);
            Ws[lc + 0][lr] = v.x; Ws[lc + 1][lr] = v.y;
            Ws[lc + 2][lr] = v.z; Ws[lc + 3][lr] = v.w;
        }
        __syncthreads();

        #pragma unroll
        for (int k = 0; k < GBK; ++k) {
            const float4 a4 = *(const float4*)&Xs[k][tm];
            const float4 b4 = *(const float4*)&Ws[k][tn];
            acc[0][0] += a4.x * b4.x; acc[0][1] += a4.x * b4.y; acc[0][2] += a4.x * b4.z; acc[0][3] += a4.x * b4.w;
            acc[1][0] += a4.y * b4.x; acc[1][1] += a4.y * b4.y; acc[1][2] += a4.y * b4.z; acc[1][3] += a4.y * b4.w;
            acc[2][0] += a4.z * b4.x; acc[2][1] += a4.z * b4.y; acc[2][2] += a4.z * b4.z; acc[2][3] += a4.z * b4.w;
            acc[3][0] += a4.w * b4.x; acc[3][1] += a4.w * b4.y; acc[3][2] += a4.w * b4.z; acc[3][3] += a4.w * b4.w;
        }
        __syncthreads();
    }

    #pragma unroll
    for (int i = 0; i < 4; ++i) {
        const int gr = bm + tm + i;
        if (gr >= M) continue;
        #pragma unroll
        for (int jj = 0; jj < 4; ++jj) {
            const int gc = bn + tn + jj;
            C[(long)gr * N + gc] = acc[i][jj] + bias[gc];
        }
    }
}

// ---------------------------------------------------------------------------
// Persistent cooperative GRU layer: all 64 timesteps in ONE launch.
// Grid: 256 blocks x 192 threads, 1 block/CU (113 KB LDS). Block owns 4
// j-columns x 3 gates; thread = (b, jl, g) computes one 1024-dot per step.
// w_hh slice (12 rows, 48KB) cached in LDS ONCE; h_{t-1} (64KB) staged per
// step; grid.sync() between steps.
// LDS pads (+4 floats, rows stay 16B-aligned):
//   ws_ rows: wave reads 4 distinct rows at same k -> bank quads disjoint.
//   hs  rows: 16 b-rows -> 2 rows per bank quad = 2-way alias = free.
// ---------------------------------------------------------------------------
__global__ __launch_bounds__(192)
void gru_layer(const float* __restrict__ gx,    // [B,T,3H]
               const float* __restrict__ w_hh,  // [3H,H]
               const float* __restrict__ b_hh,  // [3H]
               float* __restrict__ h_all,       // layer0: [B,T,H] rows b*T+t
               float* __restrict__ pingA,       // layer1 odd-t target (final h)
               float* __restrict__ pingB,       // layer1 even-t target
               int layer0)
{
    __shared__ float ws_[12][kH + 4];   // 49.3 KB  (weights, persistent)
    __shared__ float hs[kB][kH + 4];    // 65.8 KB  (h_{t-1} stage)
    __shared__ float gh_s[3][64];

    const int tid = threadIdx.x;        // 0..191
    const int b  = tid & 15;
    const int jl = (tid >> 4) & 3;
    const int g  = tid / 64;            // 0..2
    const int row_l = g * 4 + jl;       // 0..11

    // --- load weight slice once: 12 rows x 1024 floats = 3072 float4 ---
    for (int idx = tid; idx < 12 * 256; idx += 192) {
        const int r  = idx >> 8;            // 0..11
        const int kk = (idx & 255) * 4;     // 0..1020
        const long grow = (long)(r >> 2) * kH + (long)blockIdx.x * 4 + (r & 3);
        *(float4*)&ws_[r][kk] = *(const float4*)(w_hh + grow * kH + kk);
    }
    const float bias = b_hh[(long)g * kH + blockIdx.x * 4 + jl];

    cg::grid_group grid = cg::this_grid();
    __syncthreads();

    for (int t = 0; t < kT; ++t) {
        // --- stage h_{t-1} (zeros at t=0) ---
        if (t == 0) {
            for (int idx = tid; idx < kB * 256; idx += 192) {
                const int bb = idx >> 8;
                const int kk = (idx & 255) * 4;
                *(float4*)&hs[bb][kk] = make_float4(0.f, 0.f, 0.f, 0.f);
            }
        } else {
            const float* hprev = layer0
                ? nullptr
                : (((t - 1) & 1) ? pingA : pingB);
            for (int idx = tid; idx < kB * 256; idx += 192) {
                const int bb = idx >> 8;
                const int kk = (idx & 255) * 4;
                const float* src = layer0
                    ? (h_all + ((long)bb * kT + (t - 1)) * kH + kk)
                    : (hprev + (long)bb * kH + kk);
                *(float4*)&hs[bb][kk] = *(const float4*)src;
            }
        }
        __syncthreads();

        // --- 1024-dot from LDS (4 independent accumulator chains) ---
        const float* wr = &ws_[row_l][0];
        const float* hr = &hs[b][0];
        float sx = 0.f, sy = 0.f, sz = 0.f, sw = 0.f;
        #pragma unroll 8
        for (int k = 0; k < kH; k += 4) {
            const float4 w4 = *(const float4*)(wr + k);
            const float4 h4 = *(const float4*)(hr + k);
            sx += w4.x * h4.x; sy += w4.y * h4.y;
            sz += w4.z * h4.z; sw += w4.w * h4.w;
        }
        gh_s[g][jl * 16 + b] = (sx + sy) + (sz + sw) + bias;
        __syncthreads();

        // --- cell update (64 threads: 4 j x 16 b) ---
        if (tid < 64) {
            const int pb = tid & 15;
            const int pj = tid >> 4;
            const int jg = blockIdx.x * 4 + pj;
            const float* gxrow = gx + ((long)pb * kT + t) * (3 * kH);
            const float xr = gxrow[jg];
            const float xz = gxrow[kH + jg];
            const float xn = gxrow[2 * kH + jg];
            const float hr_ = gh_s[0][pj * 16 + pb];
            const float hz  = gh_s[1][pj * 16 + pb];
            const float hn  = gh_s[2][pj * 16 + pb];
            const float hp  = hs[pb][jg];           // h_{t-1} from LDS
            const float r = 1.f / (1.f + __expf(-(xr + hr_)));
            const float z = 1.f / (1.f + __expf(-(xz + hz)));
            const float n = tanhf(xn + r * hn);
            const float hnew = (1.f - z) * n + z * hp;
            float* dst = layer0
                ? (h_all + ((long)pb * kT + t) * kH + jg)
                : (((t & 1) ? pingA : pingB) + (long)pb * kH + jg);
            *dst = hnew;
        }
        __threadfence();   // make h_t visible device-wide
        grid.sync();       // all blocks step together
    }
}

// ---------------------------------------------------------------------------
// kernel_launch
// ---------------------------------------------------------------------------
extern "C" void kernel_launch(void* const* d_in, const int* in_sizes, int n_in,
                              void* d_out, int out_size, void* d_ws, size_t ws_size,
                              hipStream_t stream)
{
    const float* x        = (const float*)d_in[0];   // [16,64,4096]
    const float* w_ih_l0  = (const float*)d_in[1];   // [3072,4096]
    const float* w_hh_l0  = (const float*)d_in[2];   // [3072,1024]
    const float* b_ih_l0  = (const float*)d_in[3];   // [3072]
    const float* b_hh_l0  = (const float*)d_in[4];   // [3072]
    const float* w_ih_l1  = (const float*)d_in[5];   // [3072,1024]
    const float* w_hh_l1  = (const float*)d_in[6];   // [3072,1024]
    const float* b_ih_l1  = (const float*)d_in[7];   // [3072]
    const float* b_hh_l1  = (const float*)d_in[8];   // [3072]
    const float* dec_w    = (const float*)d_in[9];   // [4096,1024]
    const float* dec_b    = (const float*)d_in[10];  // [4096]
    float* out = (float*)d_out;                      // [16,4096]

    // Workspace layout (floats). gx1 reuses gx0's buffer (dead after layer 0).
    float* ws   = (float*)d_ws;
    float* gx0  = ws;                                   // [1024, 3072] rows (b*T+t)
    float* h1   = gx0 + (size_t)1024 * 3072;            // [1024, 1024] rows (b*T+t)
    float* bufA = h1 + (size_t)1024 * 1024;             // [16, 1024]
    float* bufB = bufA + (size_t)kB * kH;               // [16, 1024]
    float* gx1  = gx0;                                  // alias (sequential reuse)

    // Phase A: gx0 = x @ w_ih_l0^T + b_ih_l0   (M=1024, N=3072, K=4096)
    gemm_nt_bias<<<dim3(3072 / GBN, 1024 / GBM), 256, 0, stream>>>(
        x, w_ih_l0, b_ih_l0, gx0, 1024, 3072, 4096);

    // Layer 0 recurrence: one cooperative launch, h1 rows (b*T+t)
    {
        int layer0 = 1;
        void* args[] = {
            (void*)&gx0, (void*)&w_hh_l0, (void*)&b_hh_l0,
            (void*)&h1, (void*)&bufA, (void*)&bufB, (void*)&layer0
        };
        hipLaunchCooperativeKernel((void*)gru_layer, dim3(256), dim3(192),
                                   args, 0, stream);
    }

    // Phase C: gx1 = h1 @ w_ih_l1^T + b_ih_l1   (M=1024, N=3072, K=1024)
    gemm_nt_bias<<<dim3(3072 / GBN, 1024 / GBM), 256, 0, stream>>>(
        h1, w_ih_l1, b_ih_l1, gx1, 1024, 3072, 1024);

    // Layer 1 recurrence: ping-pong, final t=63 (odd) lands in bufA
    {
        int layer0 = 0;
        void* args[] = {
            (void*)&gx1, (void*)&w_hh_l1, (void*)&b_hh_l1,
            (void*)&h1, (void*)&bufA, (void*)&bufB, (void*)&layer0
        };
        hipLaunchCooperativeKernel((void*)gru_layer, dim3(256), dim3(192),
                                   args, 0, stream);
    }

    // Decoder: out = h2_last @ dec_w^T + dec_b   (M=16, N=4096, K=1024)
    gemm_nt_bias<<<dim3(4096 / GBN, 1), 256, 0, stream>>>(
        bufA, dec_w, dec_b, out, kB, 4096, 1024);
}

// Round 3
// 4591.286 us; speedup vs baseline: 1.9458x; 1.9458x over previous
//
#include <hip/hip_runtime.h>
#include <math.h>

// Problem constants (B=16, T=64, NN=4096, H=1024)
constexpr int kB = 16;
constexpr int kT = 64;
constexpr int kH = 1024;

// ---------------------------------------------------------------------------
// 64x64-tile fp32 GEMM (kept for the decoder, M=16 guard): C = X@W^T + bias
// ---------------------------------------------------------------------------
#define GBM 64
#define GBN 64
#define GBK 16
#define GPAD 4

__global__ __launch_bounds__(256)
void gemm_nt_bias(const float* __restrict__ X,   // [M,K]
                  const float* __restrict__ W,   // [N,K]
                  const float* __restrict__ bias,// [N]
                  float* __restrict__ C,         // [M,N]
                  int M, int N, int K)
{
    __shared__ float Xs[GBK][GBM + GPAD];
    __shared__ float Ws[GBK][GBN + GPAD];

    const int tid = threadIdx.x;
    const int bm = blockIdx.y * GBM;
    const int bn = blockIdx.x * GBN;
    const int tm = (tid >> 4) * 4;
    const int tn = (tid & 15) * 4;
    const int lr = tid >> 2;
    const int lc = (tid & 3) * 4;

    float acc[4][4] = {};

    for (int k0 = 0; k0 < K; k0 += GBK) {
        {
            const int gr = bm + lr;
            float4 v = make_float4(0.f, 0.f, 0.f, 0.f);
            if (gr < M) v = *(const float4*)(X + (long)gr * K + k0 + lc);
            Xs[lc + 0][lr] = v.x; Xs[lc + 1][lr] = v.y;
            Xs[lc + 2][lr] = v.z; Xs[lc + 3][lr] = v.w;
        }
        {
            const int gr = bn + lr;
            const float4 v = *(const float4*)(W + (long)gr * K + k0 + lc);
            Ws[lc + 0][lr] = v.x; Ws[lc + 1][lr] = v.y;
            Ws[lc + 2][lr] = v.z; Ws[lc + 3][lr] = v.w;
        }
        __syncthreads();

        #pragma unroll
        for (int k = 0; k < GBK; ++k) {
            const float4 a4 = *(const float4*)&Xs[k][tm];
            const float4 b4 = *(const float4*)&Ws[k][tn];
            acc[0][0] += a4.x * b4.x; acc[0][1] += a4.x * b4.y; acc[0][2] += a4.x * b4.z; acc[0][3] += a4.x * b4.w;
            acc[1][0] += a4.y * b4.x; acc[1][1] += a4.y * b4.y; acc[1][2] += a4.y * b4.z; acc[1][3] += a4.y * b4.w;
            acc[2][0] += a4.z * b4.x; acc[2][1] += a4.z * b4.y; acc[2][2] += a4.z * b4.z; acc[2][3] += a4.z * b4.w;
            acc[3][0] += a4.w * b4.x; acc[3][1] += a4.w * b4.y; acc[3][2] += a4.w * b4.z; acc[3][3] += a4.w * b4.w;
        }
        __syncthreads();
    }

    #pragma unroll
    for (int i = 0; i < 4; ++i) {
        const int gr = bm + tm + i;
        if (gr >= M) continue;
        #pragma unroll
        for (int jj = 0; jj < 4; ++jj) {
            const int gc = bn + tn + jj;
            C[(long)gr * N + gc] = acc[i][jj] + bias[gc];
        }
    }
}

// ---------------------------------------------------------------------------
// 128x128-tile fp32 GEMM, 8x8 micro-tile (split as 2x2 blocks of 4x4 so LDS
// column reads are <=2-way bank-aliased). Requires M%128==0, N%128==0, K%8==0.
// Per k: 64 FMA per 4 ds_read_b128 -> VALU-bound, not LDS-issue-bound.
// ---------------------------------------------------------------------------
__global__ __launch_bounds__(256)
void gemm128_nt_bias(const float* __restrict__ X,   // [M,K]
                     const float* __restrict__ W,   // [N,K]
                     const float* __restrict__ bias,// [N]
                     float* __restrict__ C,         // [M,N]
                     int M, int N, int K)
{
    __shared__ float Xs[8][132];
    __shared__ float Ws[8][132];

    const int tid = threadIdx.x;
    const int bm = blockIdx.y * 128;
    const int bn = blockIdx.x * 128;
    const int tx = tid & 15;           // column group
    const int ty = tid >> 4;           // row group
    const int lr = tid >> 1;           // loader row 0..127
    const int lk = (tid & 1) * 4;      // loader k {0,4}

    float acc[8][8] = {};

    for (int k0 = 0; k0 < K; k0 += 8) {
        // register prefetch (no LDS touch yet)
        const float4 xv = *(const float4*)(X + (long)(bm + lr) * K + k0 + lk);
        const float4 wv = *(const float4*)(W + (long)(bn + lr) * K + k0 + lk);
        __syncthreads();   // previous tile's readers done
        Xs[lk + 0][lr] = xv.x; Xs[lk + 1][lr] = xv.y;
        Xs[lk + 2][lr] = xv.z; Xs[lk + 3][lr] = xv.w;
        Ws[lk + 0][lr] = wv.x; Ws[lk + 1][lr] = wv.y;
        Ws[lk + 2][lr] = wv.z; Ws[lk + 3][lr] = wv.w;
        __syncthreads();

        #pragma unroll
        for (int k = 0; k < 8; ++k) {
            const float4 a0 = *(const float4*)&Xs[k][4 * ty];
            const float4 a1 = *(const float4*)&Xs[k][64 + 4 * ty];
            const float4 b0 = *(const float4*)&Ws[k][4 * tx];
            const float4 b1 = *(const float4*)&Ws[k][64 + 4 * tx];
            const float a[8] = {a0.x, a0.y, a0.z, a0.w, a1.x, a1.y, a1.z, a1.w};
            const float bb[8] = {b0.x, b0.y, b0.z, b0.w, b1.x, b1.y, b1.z, b1.w};
            #pragma unroll
            for (int i = 0; i < 8; ++i)
                #pragma unroll
                for (int j = 0; j < 8; ++j)
                    acc[i][j] += a[i] * bb[j];
        }
    }

    // epilogue: rows (4ty+i | 64+4ty+i), cols (4tx+j | 64+4tx+j), float4 stores
    #pragma unroll
    for (int i = 0; i < 8; ++i) {
        const int row = bm + ((i < 4) ? (4 * ty + i) : (64 + 4 * ty + i - 4));
        #pragma unroll
        for (int jh = 0; jh < 2; ++jh) {
            const int col = bn + ((jh == 0) ? (4 * tx) : (64 + 4 * tx));
            float4 v;
            v.x = acc[i][jh * 4 + 0] + bias[col + 0];
            v.y = acc[i][jh * 4 + 1] + bias[col + 1];
            v.z = acc[i][jh * 4 + 2] + bias[col + 2];
            v.w = acc[i][jh * 4 + 3] + bias[col + 3];
            *(float4*)(C + (long)row * N + col) = v;
        }
    }
}

// ---------------------------------------------------------------------------
// GRU timestep v3: 256 blocks x 768 threads (12 waves/CU). Block owns 4
// j-columns x 3 gates (12 rows). Thread = (b, rl, kh): kh splits the 1024-dot
// into 4 x 256 partials (chain length 64 quads, 4 indep accumulators each).
// No LDS staging: h (64 KB, L2-hot) and w (XCD-L2-resident slice) are read
// straight from global; LDS only holds the 4-way partials + gate values.
// kh = tid/192 is wave-uniform (192 = 3 waves), so intra-wave global reads
// coalesce to 4x16B (w, 16-lane broadcast) and 16x16B (h) segments.
// ---------------------------------------------------------------------------
__global__ __launch_bounds__(768)
void gru_step3(const float* __restrict__ gx_t,  // gates_x at timestep t
               long gx_bstride,
               const float* __restrict__ w_hh,  // [3H,H]
               const float* __restrict__ b_hh,  // [3H]
               const float* __restrict__ h_prev,
               long hp_bstride,
               int zero_init,
               float* __restrict__ h_out,
               long ho_bstride)
{
    __shared__ float part[4][12][16];
    __shared__ float ghs[3][64];

    const int tid = threadIdx.x;        // 0..767
    const int b  = tid & 15;
    const int rl = (tid >> 4) % 12;     // 0..11
    const int kh = tid / 192;           // 0..3, wave-uniform
    const int g  = rl >> 2;
    const int jl = rl & 3;
    const int j  = blockIdx.x * 4 + jl;
    const long row = (long)g * kH + j;

    float sx = 0.f, sy = 0.f, sz = 0.f, sw = 0.f;
    if (!zero_init) {
        const float* wp = w_hh + row * kH + kh * 256;
        const float* hp = h_prev + (long)b * hp_bstride + kh * 256;
        #pragma unroll 8
        for (int q = 0; q < 64; ++q) {
            const float4 w4 = *(const float4*)(wp + 4 * q);
            const float4 h4 = *(const float4*)(hp + 4 * q);
            sx += w4.x * h4.x; sy += w4.y * h4.y;
            sz += w4.z * h4.z; sw += w4.w * h4.w;
        }
    }
    part[kh][rl][b] = (sx + sy) + (sz + sw);
    __syncthreads();

    if (tid < 192) {                    // here tid = b + 16*rl, kh==0
        const int rb = tid & 15;
        const int rr = tid >> 4;        // 0..11
        const long rrow = (long)(rr >> 2) * kH + blockIdx.x * 4 + (rr & 3);
        const float d = part[0][rr][rb] + part[1][rr][rb]
                      + part[2][rr][rb] + part[3][rr][rb] + b_hh[rrow];
        ghs[rr >> 2][(rr & 3) * 16 + rb] = d;
    }
    __syncthreads();

    if (tid < 64) {
        const int pb = tid & 15;
        const int pj = tid >> 4;        // 0..3
        const int jg = blockIdx.x * 4 + pj;
        const float* gxrow = gx_t + (long)pb * gx_bstride;
        const float xr = gxrow[jg];
        const float xz = gxrow[kH + jg];
        const float xn = gxrow[2 * kH + jg];
        const float hr = ghs[0][pj * 16 + pb];
        const float hz = ghs[1][pj * 16 + pb];
        const float hn = ghs[2][pj * 16 + pb];
        const float hp = zero_init ? 0.f : h_prev[(long)pb * hp_bstride + jg];
        const float r = 1.f / (1.f + __expf(-(xr + hr)));
        const float z = 1.f / (1.f + __expf(-(xz + hz)));
        const float n = tanhf(xn + r * hn);
        h_out[(long)pb * ho_bstride + jg] = (1.f - z) * n + z * hp;
    }
}

// ---------------------------------------------------------------------------
// kernel_launch
// ---------------------------------------------------------------------------
extern "C" void kernel_launch(void* const* d_in, const int* in_sizes, int n_in,
                              void* d_out, int out_size, void* d_ws, size_t ws_size,
                              hipStream_t stream)
{
    const float* x        = (const float*)d_in[0];   // [16,64,4096]
    const float* w_ih_l0  = (const float*)d_in[1];   // [3072,4096]
    const float* w_hh_l0  = (const float*)d_in[2];   // [3072,1024]
    const float* b_ih_l0  = (const float*)d_in[3];   // [3072]
    const float* b_hh_l0  = (const float*)d_in[4];   // [3072]
    const float* w_ih_l1  = (const float*)d_in[5];   // [3072,1024]
    const float* w_hh_l1  = (const float*)d_in[6];   // [3072,1024]
    const float* b_ih_l1  = (const float*)d_in[7];   // [3072]
    const float* b_hh_l1  = (const float*)d_in[8];   // [3072]
    const float* dec_w    = (const float*)d_in[9];   // [4096,1024]
    const float* dec_b    = (const float*)d_in[10];  // [4096]
    float* out = (float*)d_out;                      // [16,4096]

    // Workspace layout (floats). gx1 aliases gx0 (dead after layer 0).
    float* ws   = (float*)d_ws;
    float* gx0  = ws;                                   // [1024, 3072] rows (b*T+t)
    float* h1   = gx0 + (size_t)1024 * 3072;            // [1024, 1024] rows (b*T+t)
    float* bufA = h1 + (size_t)1024 * 1024;             // [16, 1024]
    float* bufB = bufA + (size_t)kB * kH;               // [16, 1024]
    float* gx1  = gx0;

    const long gx_bstride = (long)kT * 3 * kH;          // 196608
    const long h1_bstride = (long)kT * kH;              // 65536

    // Phase A: gx0 = x @ w_ih_l0^T + b_ih_l0   (M=1024, N=3072, K=4096)
    gemm128_nt_bias<<<dim3(3072 / 128, 1024 / 128), 256, 0, stream>>>(
        x, w_ih_l0, b_ih_l0, gx0, 1024, 3072, 4096);

    // Layer 0 recurrence (h1 rows b*T+t)
    for (int t = 0; t < kT; ++t) {
        const float* hp = (t == 0) ? h1 : (h1 + (size_t)(t - 1) * kH);
        gru_step3<<<256, 768, 0, stream>>>(
            gx0 + (size_t)t * 3 * kH, gx_bstride,
            w_hh_l0, b_hh_l0,
            hp, h1_bstride, (t == 0) ? 1 : 0,
            h1 + (size_t)t * kH, h1_bstride);
    }

    // Phase C: gx1 = h1 @ w_ih_l1^T + b_ih_l1   (M=1024, N=3072, K=1024)
    gemm128_nt_bias<<<dim3(3072 / 128, 1024 / 128), 256, 0, stream>>>(
        h1, w_ih_l1, b_ih_l1, gx1, 1024, 3072, 1024);

    // Layer 1 recurrence: ping-pong, final t=63 (odd) lands in bufA
    for (int t = 0; t < kT; ++t) {
        const float* hp = (t & 1) ? bufB : bufA;
        float* ho       = (t & 1) ? bufA : bufB;
        gru_step3<<<256, 768, 0, stream>>>(
            gx1 + (size_t)t * 3 * kH, gx_bstride,
            w_hh_l1, b_hh_l1,
            hp, (long)kH, (t == 0) ? 1 : 0,
            ho, (long)kH);
    }

    // Decoder: out = h2_last @ dec_w^T + dec_b   (M=16, N=4096, K=1024)
    gemm_nt_bias<<<dim3(4096 / GBN, 1), 256, 0, stream>>>(
        bufA, dec_w, dec_b, out, kB, 4096, 1024);
}

// Round 4
// 1767.685 us; speedup vs baseline: 5.0539x; 2.5973x over previous
//
#include <hip/hip_runtime.h>
#include <math.h>

// Problem constants (B=16, T=64, NN=4096, H=1024)
constexpr int kB = 16;
constexpr int kT = 64;
constexpr int kH = 1024;

// ---------------------------------------------------------------------------
// 64x64-tile fp32 GEMM (decoder only; M=16 guard): C = X@W^T + bias
// ---------------------------------------------------------------------------
#define GBM 64
#define GBN 64
#define GBK 16
#define GPAD 4

__global__ __launch_bounds__(256)
void gemm_nt_bias(const float* __restrict__ X,   // [M,K]
                  const float* __restrict__ W,   // [N,K]
                  const float* __restrict__ bias,// [N]
                  float* __restrict__ C,         // [M,N]
                  int M, int N, int K)
{
    __shared__ float Xs[GBK][GBM + GPAD];
    __shared__ float Ws[GBK][GBN + GPAD];

    const int tid = threadIdx.x;
    const int bm = blockIdx.y * GBM;
    const int bn = blockIdx.x * GBN;
    const int tm = (tid >> 4) * 4;
    const int tn = (tid & 15) * 4;
    const int lr = tid >> 2;
    const int lc = (tid & 3) * 4;

    float acc[4][4] = {};

    for (int k0 = 0; k0 < K; k0 += GBK) {
        {
            const int gr = bm + lr;
            float4 v = make_float4(0.f, 0.f, 0.f, 0.f);
            if (gr < M) v = *(const float4*)(X + (long)gr * K + k0 + lc);
            Xs[lc + 0][lr] = v.x; Xs[lc + 1][lr] = v.y;
            Xs[lc + 2][lr] = v.z; Xs[lc + 3][lr] = v.w;
        }
        {
            const int gr = bn + lr;
            const float4 v = *(const float4*)(W + (long)gr * K + k0 + lc);
            Ws[lc + 0][lr] = v.x; Ws[lc + 1][lr] = v.y;
            Ws[lc + 2][lr] = v.z; Ws[lc + 3][lr] = v.w;
        }
        __syncthreads();

        #pragma unroll
        for (int k = 0; k < GBK; ++k) {
            const float4 a4 = *(const float4*)&Xs[k][tm];
            const float4 b4 = *(const float4*)&Ws[k][tn];
            acc[0][0] += a4.x * b4.x; acc[0][1] += a4.x * b4.y; acc[0][2] += a4.x * b4.z; acc[0][3] += a4.x * b4.w;
            acc[1][0] += a4.y * b4.x; acc[1][1] += a4.y * b4.y; acc[1][2] += a4.y * b4.z; acc[1][3] += a4.y * b4.w;
            acc[2][0] += a4.z * b4.x; acc[2][1] += a4.z * b4.y; acc[2][2] += a4.z * b4.z; acc[2][3] += a4.z * b4.w;
            acc[3][0] += a4.w * b4.x; acc[3][1] += a4.w * b4.y; acc[3][2] += a4.w * b4.z; acc[3][3] += a4.w * b4.w;
        }
        __syncthreads();
    }

    #pragma unroll
    for (int i = 0; i < 4; ++i) {
        const int gr = bm + tm + i;
        if (gr >= M) continue;
        #pragma unroll
        for (int jj = 0; jj < 4; ++jj) {
            const int gc = bn + tn + jj;
            C[(long)gr * N + gc] = acc[i][jj] + bias[gc];
        }
    }
}

// ---------------------------------------------------------------------------
// 64(M)x128(N)-tile fp32 GEMM, 4x8 micro-tile, 256 threads.
// Grid = (N/128, M/64) = 24x16 = 384 blocks -> >=1.5 blocks/CU (occupancy fix
// vs the 192-block 128x128 version). Requires M%64==0, N%128==0, K%8==0.
// LDS ~6.4 KB; per k: 3 ds_read_b128 per 32 FMA. Column reads <=2-way alias.
// ---------------------------------------------------------------------------
__global__ __launch_bounds__(256)
void gemm_a(const float* __restrict__ X,   // [M,K]
            const float* __restrict__ W,   // [N,K]
            const float* __restrict__ bias,// [N]
            float* __restrict__ C,         // [M,N]
            int M, int N, int K)
{
    __shared__ float Xs[8][64 + 4];
    __shared__ float Ws[8][128 + 4];

    const int tid = threadIdx.x;
    const int bm = blockIdx.y * 64;
    const int bn = blockIdx.x * 128;
    const int tx = tid & 15;          // 0..15 col group
    const int ty = tid >> 4;          // 0..15 row group
    const int xr = tid >> 1;          // X loader row (threads 0..127)
    const int wr = tid >> 1;          // W loader row 0..127
    const int lk = (tid & 1) * 4;     // loader k {0,4}

    float acc[4][8] = {};

    for (int k0 = 0; k0 < K; k0 += 8) {
        float4 xv = make_float4(0.f, 0.f, 0.f, 0.f);
        if (tid < 128) xv = *(const float4*)(X + (long)(bm + xr) * K + k0 + lk);
        const float4 wv = *(const float4*)(W + (long)(bn + wr) * K + k0 + lk);
        __syncthreads();   // previous tile's readers done
        if (tid < 128) {
            Xs[lk + 0][xr] = xv.x; Xs[lk + 1][xr] = xv.y;
            Xs[lk + 2][xr] = xv.z; Xs[lk + 3][xr] = xv.w;
        }
        Ws[lk + 0][wr] = wv.x; Ws[lk + 1][wr] = wv.y;
        Ws[lk + 2][wr] = wv.z; Ws[lk + 3][wr] = wv.w;
        __syncthreads();

        #pragma unroll
        for (int k = 0; k < 8; ++k) {
            const float4 a4 = *(const float4*)&Xs[k][4 * ty];
            const float4 b0 = *(const float4*)&Ws[k][4 * tx];
            const float4 b1 = *(const float4*)&Ws[k][64 + 4 * tx];
            const float a[4] = {a4.x, a4.y, a4.z, a4.w};
            const float bb[8] = {b0.x, b0.y, b0.z, b0.w, b1.x, b1.y, b1.z, b1.w};
            #pragma unroll
            for (int i = 0; i < 4; ++i)
                #pragma unroll
                for (int j = 0; j < 8; ++j)
                    acc[i][j] += a[i] * bb[j];
        }
    }

    #pragma unroll
    for (int i = 0; i < 4; ++i) {
        const int row = bm + 4 * ty + i;
        #pragma unroll
        for (int jh = 0; jh < 2; ++jh) {
            const int col = bn + jh * 64 + 4 * tx;
            float4 v;
            v.x = acc[i][jh * 4 + 0] + bias[col + 0];
            v.y = acc[i][jh * 4 + 1] + bias[col + 1];
            v.z = acc[i][jh * 4 + 2] + bias[col + 2];
            v.w = acc[i][jh * 4 + 3] + bias[col + 3];
            *(float4*)(C + (long)row * N + col) = v;
        }
    }
}

// ---------------------------------------------------------------------------
// GRU timestep v4. 256 blocks x 256 threads (4 waves). Block owns rows
// {g*1024 + bx*4 + jl : g=0..2, jl=0..3}. Wave g (0..2) computes gate g:
// lane owns k-quads {4*lane + 256*i : i=0..3} (dense LDS pattern) with
// acc[jl*16+b] in registers -> w_hh read from L2 exactly once per block,
// h element read once per wave (b-reuse in registers, not thread replication).
// k-reduction = in-register wave butterfly (63 shfl+add); final lane holds
// gh for index brev6(lane). Wave 3 helps stage h, then does the cell update.
// ---------------------------------------------------------------------------
__device__ __forceinline__ int brev6(int L) {
    return ((L & 1) << 5) | ((L & 2) << 3) | ((L & 4) << 1) |
           ((L & 8) >> 1) | ((L & 16) >> 3) | ((L & 32) >> 5);
}

__global__ __launch_bounds__(256)
void gru_step4(const float* __restrict__ gx_t,  // gates_x at timestep t
               long gx_bstride,
               const float* __restrict__ w_hh,  // [3H,H]
               const float* __restrict__ b_hh,  // [3H]
               const float* __restrict__ h_prev,
               long hp_bstride,
               int zero_init,
               float* __restrict__ h_out,
               long ho_bstride)
{
    __shared__ float hs[kB][kH];     // 64 KB h_{t-1} stage
    __shared__ float ghs[3][64];     // gate values [g][jl*16+b]

    const int tid  = threadIdx.x;    // 0..255
    const int lane = tid & 63;
    const int wid  = tid >> 6;       // 0..3; waves 0..2 = gates
    const int bx4  = blockIdx.x * 4;

    // --- stage h_{t-1} into LDS (all 4 waves) ---
    // thread t: b = t>>4, c2 = t&15; writes k-quads {c2 + 16*j, j=0..15}
    {
        const int b  = tid >> 4;
        const int c2 = tid & 15;
        if (zero_init) {
            #pragma unroll
            for (int j = 0; j < 16; ++j)
                *(float4*)&hs[b][(c2 + 16 * j) * 4] = make_float4(0.f, 0.f, 0.f, 0.f);
        } else {
            const float* src = h_prev + (long)b * hp_bstride;
            #pragma unroll
            for (int j = 0; j < 16; ++j)
                *(float4*)&hs[b][(c2 + 16 * j) * 4] =
                    *(const float4*)(src + (c2 + 16 * j) * 4);
        }
    }
    __syncthreads();

    if (wid < 3) {
        const int g = wid;
        float v[64];
        #pragma unroll
        for (int i = 0; i < 64; ++i) v[i] = 0.f;

        if (!zero_init) {
            #pragma unroll
            for (int i = 0; i < 4; ++i) {
                const int kq = 4 * lane + 256 * i;
                float4 wv[4];
                #pragma unroll
                for (int jl = 0; jl < 4; ++jl)
                    wv[jl] = *(const float4*)(w_hh + ((long)g * kH + bx4 + jl) * kH + kq);
                #pragma unroll
                for (int b = 0; b < 16; ++b) {
                    const float4 h4 = *(const float4*)&hs[b][kq];
                    #pragma unroll
                    for (int jl = 0; jl < 4; ++jl) {
                        v[jl * 16 + b] += wv[jl].x * h4.x + wv[jl].y * h4.y
                                        + wv[jl].z * h4.z + wv[jl].w * h4.w;
                    }
                }
            }
        }

        // --- butterfly reduce over 64 lanes (sums over all k) ---
        int n = 64;
        #pragma unroll
        for (int s = 0; s < 6; ++s) {
            const int m = 1 << s;
            const int h = n >> 1;
            const bool up = (lane & m) != 0;
            #pragma unroll
            for (int i = 0; i < h; ++i) {
                const float send = up ? v[i] : v[i + h];
                const float recv = __shfl_xor(send, m, 64);
                v[i] = (up ? v[i + h] : v[i]) + recv;
            }
            n = h;
        }
        // lane holds gh for idx = brev6(lane): jl = idx>>4, b = idx&15
        const int idx = brev6(lane);
        const int jl = idx >> 4;
        ghs[g][idx] = v[0] + b_hh[(long)g * kH + bx4 + jl];
    }
    __syncthreads();

    // --- cell update on wave 3 (64 threads) ---
    if (wid == 3) {
        const int pb = lane & 15;
        const int pj = lane >> 4;            // 0..3
        const int jg = bx4 + pj;
        const float* gxrow = gx_t + (long)pb * gx_bstride;
        const float xr = gxrow[jg];
        const float xz = gxrow[kH + jg];
        const float xn = gxrow[2 * kH + jg];
        const float hr = ghs[0][pj * 16 + pb];
        const float hz = ghs[1][pj * 16 + pb];
        const float hn = ghs[2][pj * 16 + pb];
        const float hp = hs[pb][jg];
        const float r = 1.f / (1.f + __expf(-(xr + hr)));
        const float z = 1.f / (1.f + __expf(-(xz + hz)));
        const float nn = tanhf(xn + r * hn);
        h_out[(long)pb * ho_bstride + jg] = (1.f - z) * nn + z * hp;
    }
}

// ---------------------------------------------------------------------------
// kernel_launch
// ---------------------------------------------------------------------------
extern "C" void kernel_launch(void* const* d_in, const int* in_sizes, int n_in,
                              void* d_out, int out_size, void* d_ws, size_t ws_size,
                              hipStream_t stream)
{
    const float* x        = (const float*)d_in[0];   // [16,64,4096]
    const float* w_ih_l0  = (const float*)d_in[1];   // [3072,4096]
    const float* w_hh_l0  = (const float*)d_in[2];   // [3072,1024]
    const float* b_ih_l0  = (const float*)d_in[3];   // [3072]
    const float* b_hh_l0  = (const float*)d_in[4];   // [3072]
    const float* w_ih_l1  = (const float*)d_in[5];   // [3072,1024]
    const float* w_hh_l1  = (const float*)d_in[6];   // [3072,1024]
    const float* b_ih_l1  = (const float*)d_in[7];   // [3072]
    const float* b_hh_l1  = (const float*)d_in[8];   // [3072]
    const float* dec_w    = (const float*)d_in[9];   // [4096,1024]
    const float* dec_b    = (const float*)d_in[10];  // [4096]
    float* out = (float*)d_out;                      // [16,4096]

    // Workspace layout (floats). gx1 aliases gx0 (dead after layer 0).
    float* ws   = (float*)d_ws;
    float* gx0  = ws;                                   // [1024, 3072] rows (b*T+t)
    float* h1   = gx0 + (size_t)1024 * 3072;            // [1024, 1024] rows (b*T+t)
    float* bufA = h1 + (size_t)1024 * 1024;             // [16, 1024]
    float* bufB = bufA + (size_t)kB * kH;               // [16, 1024]
    float* gx1  = gx0;

    const long gx_bstride = (long)kT * 3 * kH;          // 196608
    const long h1_bstride = (long)kT * kH;              // 65536

    // Phase A: gx0 = x @ w_ih_l0^T + b_ih_l0   (M=1024, N=3072, K=4096)
    gemm_a<<<dim3(3072 / 128, 1024 / 64), 256, 0, stream>>>(
        x, w_ih_l0, b_ih_l0, gx0, 1024, 3072, 4096);

    // Layer 0 recurrence (h1 rows b*T+t)
    for (int t = 0; t < kT; ++t) {
        const float* hp = (t == 0) ? h1 : (h1 + (size_t)(t - 1) * kH);
        gru_step4<<<256, 256, 0, stream>>>(
            gx0 + (size_t)t * 3 * kH, gx_bstride,
            w_hh_l0, b_hh_l0,
            hp, h1_bstride, (t == 0) ? 1 : 0,
            h1 + (size_t)t * kH, h1_bstride);
    }

    // Phase C: gx1 = h1 @ w_ih_l1^T + b_ih_l1   (M=1024, N=3072, K=1024)
    gemm_a<<<dim3(3072 / 128, 1024 / 64), 256, 0, stream>>>(
        h1, w_ih_l1, b_ih_l1, gx1, 1024, 3072, 1024);

    // Layer 1 recurrence: ping-pong, final t=63 (odd) lands in bufA
    for (int t = 0; t < kT; ++t) {
        const float* hp = (t & 1) ? bufB : bufA;
        float* ho       = (t & 1) ? bufA : bufB;
        gru_step4<<<256, 256, 0, stream>>>(
            gx1 + (size_t)t * 3 * kH, gx_bstride,
            w_hh_l1, b_hh_l1,
            hp, (long)kH, (t == 0) ? 1 : 0,
            ho, (long)kH);
    }

    // Decoder: out = h2_last @ dec_w^T + dec_b   (M=16, N=4096, K=1024)
    gemm_nt_bias<<<dim3(4096 / GBN, 1), 256, 0, stream>>>(
        bufA, dec_w, dec_b, out, kB, 4096, 1024);
}